// Round 1
// baseline (2043.032 us; speedup 1.0000x reference)
//
#include <hip/hip_runtime.h>

#define B_ 2
#define T_ 2048
#define C_ 1024
#define H_ 16
#define DH_ 64

// ---------------------------------------------------------------------------
// Kernel 1: fused QKV projection.  y = x @ W + b, output in [B*H][T][DH].
// 128x128 tile, BK=16, 256 threads, 8x8 accumulators per thread. fp32.
// ---------------------------------------------------------------------------
__global__ __launch_bounds__(256) void qkv_proj_kernel(
    const float* __restrict__ x,
    const float* __restrict__ Wq, const float* __restrict__ bq,
    const float* __restrict__ Wk, const float* __restrict__ bk,
    const float* __restrict__ Wv, const float* __restrict__ bv,
    float* __restrict__ qb, float* __restrict__ kb, float* __restrict__ vb)
{
    const int z = blockIdx.z;
    const float* __restrict__ W    = (z == 0) ? Wq : (z == 1) ? Wk : Wv;
    const float* __restrict__ bias = (z == 0) ? bq : (z == 1) ? bk : bv;
    float* __restrict__ outp       = (z == 0) ? qb : (z == 1) ? kb : vb;

    __shared__ float As[16][132];   // As[kk][m], stride 132 keeps 16B align + bank spread
    __shared__ float Bs[16][132];   // Bs[kk][n]

    const int m0 = blockIdx.x * 128;
    const int n0 = blockIdx.y * 128;
    const int tid = threadIdx.x;
    const int tx = tid & 15;        // 16 col-groups of 8
    const int ty = tid >> 4;        // 16 row-groups of 8

    float acc[8][8];
#pragma unroll
    for (int i = 0; i < 8; i++)
#pragma unroll
        for (int j = 0; j < 8; j++) acc[i][j] = 0.f;

    const int arow = tid >> 2;      // 0..63
    const int ac4  = tid & 3;       // k-group (float4)
    const int brow = tid >> 5;      // 0..7
    const int bc4  = tid & 31;      // n-group (float4)

    for (int k0 = 0; k0 < C_; k0 += 16) {
        float4 a0 = *(const float4*)(x + (size_t)(m0 + arow)      * C_ + k0 + 4 * ac4);
        float4 a1 = *(const float4*)(x + (size_t)(m0 + arow + 64) * C_ + k0 + 4 * ac4);
        float4 b0 = *(const float4*)(W + (size_t)(k0 + brow)     * C_ + n0 + 4 * bc4);
        float4 b1 = *(const float4*)(W + (size_t)(k0 + brow + 8) * C_ + n0 + 4 * bc4);
        __syncthreads();
        As[4*ac4+0][arow] = a0.x; As[4*ac4+1][arow] = a0.y;
        As[4*ac4+2][arow] = a0.z; As[4*ac4+3][arow] = a0.w;
        As[4*ac4+0][arow+64] = a1.x; As[4*ac4+1][arow+64] = a1.y;
        As[4*ac4+2][arow+64] = a1.z; As[4*ac4+3][arow+64] = a1.w;
        *(float4*)&Bs[brow    ][4*bc4] = b0;
        *(float4*)&Bs[brow + 8][4*bc4] = b1;
        __syncthreads();
#pragma unroll
        for (int kk = 0; kk < 16; kk++) {
            float4 av0 = *(const float4*)&As[kk][ty*8];
            float4 av1 = *(const float4*)&As[kk][ty*8+4];
            float4 bv0 = *(const float4*)&Bs[kk][tx*8];
            float4 bv1 = *(const float4*)&Bs[kk][tx*8+4];
            float ar[8] = {av0.x,av0.y,av0.z,av0.w,av1.x,av1.y,av1.z,av1.w};
            float br[8] = {bv0.x,bv0.y,bv0.z,bv0.w,bv1.x,bv1.y,bv1.z,bv1.w};
#pragma unroll
            for (int i = 0; i < 8; i++)
#pragma unroll
                for (int j = 0; j < 8; j++)
                    acc[i][j] = fmaf(ar[i], br[j], acc[i][j]);
        }
    }

    // Epilogue: +bias, write to [B*H][T][DH].  Each thread's 8 cols stay in one head.
    const int n = n0 + tx * 8;
    const int h = n >> 6;
    const int d = n & 63;
    float4 bb0 = *(const float4*)(bias + n);
    float4 bb1 = *(const float4*)(bias + n + 4);
#pragma unroll
    for (int i = 0; i < 8; i++) {
        int mrow = m0 + ty * 8 + i;
        int bidx = mrow >> 11;          // / T_
        int t    = mrow & (T_ - 1);
        size_t base = ((size_t)(bidx * H_ + h) * T_ + t) * DH_ + d;
        float4 r0 = {acc[i][0]+bb0.x, acc[i][1]+bb0.y, acc[i][2]+bb0.z, acc[i][3]+bb0.w};
        float4 r1 = {acc[i][4]+bb1.x, acc[i][5]+bb1.y, acc[i][6]+bb1.z, acc[i][7]+bb1.w};
        *(float4*)(outp + base)     = r0;
        *(float4*)(outp + base + 4) = r1;
    }
}

// ---------------------------------------------------------------------------
// Kernel 2: masked attention. One wave per query row, 4 rows (waves) / block.
// Scores for the whole row (2048 keys / 64 lanes = 32 per lane) held in regs:
// pass A computes scores over K tiles, exact softmax, pass B accumulates over
// V tiles. K/V tiles staged in one 64x68 LDS buffer (float4-aligned, bank-spread).
// ---------------------------------------------------------------------------
__global__ __launch_bounds__(256) void attn_kernel(
    const float* __restrict__ qb, const float* __restrict__ kb,
    const float* __restrict__ vb, const int* __restrict__ mask,
    float* __restrict__ out)
{
    __shared__ float Ks[64][68];

    const int bid  = blockIdx.x;
    const int bh   = bid >> 9;          // / (T_/4)
    const int qt   = bid & 511;
    const int b    = bh >> 4;
    const int h    = bh & 15;
    const int w    = threadIdx.x >> 6;  // wave id 0..3
    const int lane = threadIdx.x & 63;
    const int q    = qt * 4 + w;

    const int* __restrict__ mrow = mask + b * T_;
    const bool qvalid = (mrow[q] != 0);

    // q row into registers (wave-uniform address -> broadcast loads)
    const float4* qrow = (const float4*)(qb + ((size_t)bh * T_ + q) * DH_);
    float4 q4[16];
#pragma unroll
    for (int i = 0; i < 16; i++) q4[i] = qrow[i];

    float sc[32];
    float mloc = -1e30f;

    // ---- Pass A: scores (lane l owns keys  t*64 + l) ----
#pragma unroll
    for (int t = 0; t < 32; t++) {
        const float4* src = (const float4*)(kb + ((size_t)bh * T_ + t * 64) * DH_);
        __syncthreads();
#pragma unroll
        for (int i = 0; i < 4; i++) {
            int idx = (int)threadIdx.x + i * 256;       // 1024 float4s
            float4 vv = src[idx];
            *(float4*)&Ks[idx >> 4][(idx & 15) * 4] = vv;
        }
        __syncthreads();
        float a = 0.f;
        const float4* krow = (const float4*)&Ks[lane][0];
#pragma unroll
        for (int dd = 0; dd < 16; dd++) {
            float4 kv = krow[dd];
            float4 qv = q4[dd];
            a = fmaf(qv.x, kv.x, a); a = fmaf(qv.y, kv.y, a);
            a = fmaf(qv.z, kv.z, a); a = fmaf(qv.w, kv.w, a);
        }
        int j = t * 64 + lane;
        float sval = (mrow[j] != 0) ? a * 0.125f : -1e30f;   // 1/sqrt(64)=0.125
        sc[t] = sval;
        mloc = fmaxf(mloc, sval);
    }

    // row max across the wave
#pragma unroll
    for (int off = 32; off >= 1; off >>= 1)
        mloc = fmaxf(mloc, __shfl_xor(mloc, off, 64));

    float ssum = 0.f;
#pragma unroll
    for (int t = 0; t < 32; t++) { sc[t] = __expf(sc[t] - mloc); ssum += sc[t]; }
#pragma unroll
    for (int off = 32; off >= 1; off >>= 1) ssum += __shfl_xor(ssum, off, 64);
    const float inv = 1.0f / ssum;

    // ---- Pass B: o += p * V ----
    float4 o4[16];
#pragma unroll
    for (int i = 0; i < 16; i++) o4[i] = make_float4(0.f, 0.f, 0.f, 0.f);

#pragma unroll
    for (int t = 0; t < 32; t++) {
        const float4* src = (const float4*)(vb + ((size_t)bh * T_ + t * 64) * DH_);
        __syncthreads();
#pragma unroll
        for (int i = 0; i < 4; i++) {
            int idx = (int)threadIdx.x + i * 256;
            float4 vv = src[idx];
            *(float4*)&Ks[idx >> 4][(idx & 15) * 4] = vv;
        }
        __syncthreads();
        const float p = sc[t] * inv;
        const float4* vrow = (const float4*)&Ks[lane][0];
#pragma unroll
        for (int dd = 0; dd < 16; dd++) {
            float4 vv = vrow[dd];
            o4[dd].x = fmaf(p, vv.x, o4[dd].x);
            o4[dd].y = fmaf(p, vv.y, o4[dd].y);
            o4[dd].z = fmaf(p, vv.z, o4[dd].z);
            o4[dd].w = fmaf(p, vv.w, o4[dd].w);
        }
    }

    // all-reduce partial o across the 64 lanes (butterfly)
#pragma unroll
    for (int off = 32; off >= 1; off >>= 1) {
#pragma unroll
        for (int dd = 0; dd < 16; dd++) {
            o4[dd].x += __shfl_xor(o4[dd].x, off, 64);
            o4[dd].y += __shfl_xor(o4[dd].y, off, 64);
            o4[dd].z += __shfl_xor(o4[dd].z, off, 64);
            o4[dd].w += __shfl_xor(o4[dd].w, off, 64);
        }
    }

    float4* orow = (float4*)(out + ((size_t)(b * T_ + q)) * C_ + h * DH_);
    if (qvalid) {
#pragma unroll
        for (int dd = 0; dd < 16; dd++)
            if (lane == dd) orow[dd] = o4[dd];      // fully-masked rows -> 0 handled below
    } else {
        if (lane < 16) orow[lane] = make_float4(0.f, 0.f, 0.f, 0.f);
    }
}

// ---------------------------------------------------------------------------
extern "C" void kernel_launch(void* const* d_in, const int* in_sizes, int n_in,
                              void* d_out, int out_size, void* d_ws, size_t ws_size,
                              hipStream_t stream)
{
    (void)in_sizes; (void)n_in; (void)out_size; (void)ws_size;
    const float* x  = (const float*)d_in[0];
    const float* Wq = (const float*)d_in[1];
    const float* bq = (const float*)d_in[2];
    const float* Wk = (const float*)d_in[3];
    const float* bk = (const float*)d_in[4];
    const float* Wv = (const float*)d_in[5];
    const float* bv = (const float*)d_in[6];
    const int* mask = (const int*)d_in[7];
    float* out = (float*)d_out;

    float* qb = (float*)d_ws;                       // 3 x 16 MB in workspace
    float* kb = qb + (size_t)B_ * H_ * T_ * DH_;
    float* vb = kb + (size_t)B_ * H_ * T_ * DH_;

    qkv_proj_kernel<<<dim3(32, 8, 3), 256, 0, stream>>>(
        x, Wq, bq, Wk, bk, Wv, bv, qb, kb, vb);
    attn_kernel<<<16384, 256, 0, stream>>>(qb, kb, vb, mask, out);
}

// Round 2
// 601.462 us; speedup vs baseline: 3.3968x; 3.3968x over previous
//
#include <hip/hip_runtime.h>

#define B_ 2
#define T_ 2048
#define C_ 1024
#define H_ 16
#define DH_ 64

typedef __attribute__((ext_vector_type(8))) short short8;   // 8 bf16 (4 VGPRs)
typedef __attribute__((ext_vector_type(4))) float f32x4;

__device__ __forceinline__ unsigned short f2bf(float f) {
    union { float f; unsigned u; } un; un.f = f;
    unsigned r = un.u + 0x7FFF + ((un.u >> 16) & 1);   // RNE
    return (unsigned short)(r >> 16);
}

// ---------------------------------------------------------------------------
// Kernel 1: fused QKV projection (fp32 GEMM), epilogue converts to bf16.
// q,k -> [bh][T][64] bf16 ; v -> transposed [bh][64][T] bf16.
// ---------------------------------------------------------------------------
__global__ __launch_bounds__(256) void qkv_proj_kernel(
    const float* __restrict__ x,
    const float* __restrict__ Wq, const float* __restrict__ bq,
    const float* __restrict__ Wk, const float* __restrict__ bk,
    const float* __restrict__ Wv, const float* __restrict__ bv,
    unsigned short* __restrict__ qb, unsigned short* __restrict__ kb,
    unsigned short* __restrict__ vt)
{
    const int z = blockIdx.z;
    const float* __restrict__ W    = (z == 0) ? Wq : (z == 1) ? Wk : Wv;
    const float* __restrict__ bias = (z == 0) ? bq : (z == 1) ? bk : bv;

    __shared__ float As[16][132];
    __shared__ float Bs[16][132];

    const int m0 = blockIdx.x * 128;
    const int n0 = blockIdx.y * 128;
    const int tid = threadIdx.x;
    const int tx = tid & 15;
    const int ty = tid >> 4;

    float acc[8][8];
#pragma unroll
    for (int i = 0; i < 8; i++)
#pragma unroll
        for (int j = 0; j < 8; j++) acc[i][j] = 0.f;

    const int arow = tid >> 2;
    const int ac4  = tid & 3;
    const int brow = tid >> 5;
    const int bc4  = tid & 31;

    for (int k0 = 0; k0 < C_; k0 += 16) {
        float4 a0 = *(const float4*)(x + (size_t)(m0 + arow)      * C_ + k0 + 4 * ac4);
        float4 a1 = *(const float4*)(x + (size_t)(m0 + arow + 64) * C_ + k0 + 4 * ac4);
        float4 b0 = *(const float4*)(W + (size_t)(k0 + brow)     * C_ + n0 + 4 * bc4);
        float4 b1 = *(const float4*)(W + (size_t)(k0 + brow + 8) * C_ + n0 + 4 * bc4);
        __syncthreads();
        As[4*ac4+0][arow] = a0.x; As[4*ac4+1][arow] = a0.y;
        As[4*ac4+2][arow] = a0.z; As[4*ac4+3][arow] = a0.w;
        As[4*ac4+0][arow+64] = a1.x; As[4*ac4+1][arow+64] = a1.y;
        As[4*ac4+2][arow+64] = a1.z; As[4*ac4+3][arow+64] = a1.w;
        *(float4*)&Bs[brow    ][4*bc4] = b0;
        *(float4*)&Bs[brow + 8][4*bc4] = b1;
        __syncthreads();
#pragma unroll
        for (int kk = 0; kk < 16; kk++) {
            float4 av0 = *(const float4*)&As[kk][ty*8];
            float4 av1 = *(const float4*)&As[kk][ty*8+4];
            float4 bv0 = *(const float4*)&Bs[kk][tx*8];
            float4 bv1 = *(const float4*)&Bs[kk][tx*8+4];
            float ar[8] = {av0.x,av0.y,av0.z,av0.w,av1.x,av1.y,av1.z,av1.w};
            float br[8] = {bv0.x,bv0.y,bv0.z,bv0.w,bv1.x,bv1.y,bv1.z,bv1.w};
#pragma unroll
            for (int i = 0; i < 8; i++)
#pragma unroll
                for (int j = 0; j < 8; j++)
                    acc[i][j] = fmaf(ar[i], br[j], acc[i][j]);
        }
    }

    const int n = n0 + tx * 8;        // column (within C)
    const int h = n >> 6;             // head
    const int d = n & 63;             // dh base (multiple of 8)
    float bb[8];
#pragma unroll
    for (int j = 0; j < 8; j++) bb[j] = bias[n + j];

    if (z < 2) {
        unsigned short* outp = (z == 0) ? qb : kb;
#pragma unroll
        for (int i = 0; i < 8; i++) {
            int mrow = m0 + ty * 8 + i;
            int bidx = mrow >> 11;
            int t    = mrow & (T_ - 1);
            unsigned short u[8];
#pragma unroll
            for (int j = 0; j < 8; j++) u[j] = f2bf(acc[i][j] + bb[j]);
            size_t base = ((size_t)((bidx * H_ + h) * T_ + t)) * DH_ + d;
            *(uint4*)(outp + base) = *(const uint4*)u;   // 16B, aligned (d%8==0)
        }
    } else {
        // V transposed: vt[bh][dh][t]
        int t0   = m0 + ty * 8;
        int bidx = t0 >> 11;
        int t    = t0 & (T_ - 1);
#pragma unroll
        for (int j = 0; j < 8; j++) {
            unsigned short u[8];
#pragma unroll
            for (int i = 0; i < 8; i++) u[i] = f2bf(acc[i][j] + bb[j]);
            size_t base = ((size_t)((bidx * H_ + h) * DH_ + d + j)) * T_ + t;
            *(uint4*)(vt + base) = *(const uint4*)u;
        }
    }
}

// ---------------------------------------------------------------------------
// Kernel 2: MFMA flash attention, no-max softmax (scores bounded).
// 4 waves/block, each wave owns 16 q rows; block = 64 q rows of one (b,h).
// Layouts (verified m120 mapping for mfma_f32_16x16x32_bf16):
//   A[m=lane&15][k=quad*8+j], B[n=lane&15][k=quad*8+j], C/D row=quad*4+reg col=lane&15
// ---------------------------------------------------------------------------
__global__ __launch_bounds__(256) void attn_mfma_kernel(
    const unsigned short* __restrict__ qb,  // [32][2048][64] bf16
    const unsigned short* __restrict__ kb,  // [32][2048][64] bf16
    const unsigned short* __restrict__ vt,  // [32][64][2048] bf16
    const int* __restrict__ mask,           // [2][2048]
    float* __restrict__ out)                // [2][2048][1024]
{
    __shared__ unsigned short Pb[4][16][72];  // wave-private P buffers, pitch 72 (144B, 16B-aligned rows)

    const int bh   = blockIdx.y;
    const int b    = bh >> 4;
    const int h    = bh & 15;
    const int wv   = threadIdx.x >> 6;
    const int lane = threadIdx.x & 63;
    const int l15  = lane & 15;
    const int quad = lane >> 4;
    const int q0   = blockIdx.x * 64 + wv * 16;

    const int* __restrict__ mrow = mask + b * T_;

    // Q fragments (held all loop): lane -> Q[q0+l15][quad*8 .. +7 (+32)]
    const unsigned short* qbase = qb + ((size_t)bh * T_ + q0 + l15) * DH_ + quad * 8;
    short8 qf0 = *(const short8*)(qbase);
    short8 qf1 = *(const short8*)(qbase + 32);

    const unsigned short* kbh = kb + (size_t)bh * T_ * DH_;
    const unsigned short* vbh = vt + (size_t)bh * DH_ * T_;

    f32x4 o[4];
#pragma unroll
    for (int n = 0; n < 4; n++) o[n] = (f32x4){0.f, 0.f, 0.f, 0.f};
    float lsum[4] = {0.f, 0.f, 0.f, 0.f};

    for (int kt = 0; kt < 32; ++kt) {
        const int kbase = kt * 64;

        // ---- S = Q K^T : 4 n-subtiles of 16 keys, K-dim 64 = 2 MFMAs each ----
        f32x4 s[4];
#pragma unroll
        for (int n = 0; n < 4; ++n) {
            const unsigned short* kptr = kbh + (size_t)(kbase + n * 16 + l15) * DH_ + quad * 8;
            short8 kf0 = *(const short8*)(kptr);
            short8 kf1 = *(const short8*)(kptr + 32);
            f32x4 acc = (f32x4){0.f, 0.f, 0.f, 0.f};
            acc = __builtin_amdgcn_mfma_f32_16x16x32_bf16(qf0, kf0, acc, 0, 0, 0);
            acc = __builtin_amdgcn_mfma_f32_16x16x32_bf16(qf1, kf1, acc, 0, 0, 0);
            s[n] = acc;
        }

        // ---- p = exp(s/8) * key_mask ; accumulate per-row l; P -> LDS bf16 ----
#pragma unroll
        for (int n = 0; n < 4; ++n) {
            float km = (mrow[kbase + n * 16 + l15] != 0) ? 1.f : 0.f;
#pragma unroll
            for (int r = 0; r < 4; ++r) {
                float sv = fminf(s[n][r] * 0.125f, 60.f);
                float p = __expf(sv) * km;
                lsum[r] += p;
                Pb[wv][quad * 4 + r][n * 16 + l15] = f2bf(p);
            }
        }

        // ---- read P back in A-operand layout (same-wave DS ordering) ----
        const unsigned short* prow = &Pb[wv][l15][quad * 8];
        short8 pf0 = *(const short8*)(prow);
        short8 pf1 = *(const short8*)(prow + 32);

        // ---- O += P V : B-frags straight from transposed V ----
#pragma unroll
        for (int n = 0; n < 4; ++n) {
            const unsigned short* vptr = vbh + (size_t)(n * 16 + l15) * T_ + kbase + quad * 8;
            short8 vf0 = *(const short8*)(vptr);
            short8 vf1 = *(const short8*)(vptr + 32);
            o[n] = __builtin_amdgcn_mfma_f32_16x16x32_bf16(pf0, vf0, o[n], 0, 0, 0);
            o[n] = __builtin_amdgcn_mfma_f32_16x16x32_bf16(pf1, vf1, o[n], 0, 0, 0);
        }
    }

    // ---- finalize: reduce per-row l over the 16 lanes of each quad ----
#pragma unroll
    for (int r = 0; r < 4; ++r) {
#pragma unroll
        for (int off = 1; off < 16; off <<= 1)
            lsum[r] += __shfl_xor(lsum[r], off, 64);
    }

    float inv[4];
#pragma unroll
    for (int r = 0; r < 4; ++r) {
        int qrow = q0 + quad * 4 + r;
        bool valid = (mrow[qrow] != 0) && (lsum[r] > 0.f);
        inv[r] = valid ? (1.0f / lsum[r]) : 0.f;
    }

    // O element (row=quad*4+r, col=n*16+l15) -> out[b][q0+row][h*64+col]
#pragma unroll
    for (int r = 0; r < 4; ++r) {
        int qrow = q0 + quad * 4 + r;
        float* orow = out + ((size_t)(b * T_ + qrow)) * C_ + h * DH_;
#pragma unroll
        for (int n = 0; n < 4; ++n)
            orow[n * 16 + l15] = o[n][r] * inv[r];
    }
}

// ---------------------------------------------------------------------------
extern "C" void kernel_launch(void* const* d_in, const int* in_sizes, int n_in,
                              void* d_out, int out_size, void* d_ws, size_t ws_size,
                              hipStream_t stream)
{
    (void)in_sizes; (void)n_in; (void)out_size; (void)ws_size;
    const float* x  = (const float*)d_in[0];
    const float* Wq = (const float*)d_in[1];
    const float* bq = (const float*)d_in[2];
    const float* Wk = (const float*)d_in[3];
    const float* bk = (const float*)d_in[4];
    const float* Wv = (const float*)d_in[5];
    const float* bv = (const float*)d_in[6];
    const int* mask = (const int*)d_in[7];
    float* out = (float*)d_out;

    const size_t elems = (size_t)B_ * H_ * T_ * DH_;   // 4 Mi elements
    unsigned short* qb = (unsigned short*)d_ws;         // 8 MB
    unsigned short* kb = qb + elems;                    // 8 MB
    unsigned short* vt = kb + elems;                    // 8 MB (transposed)

    qkv_proj_kernel<<<dim3(32, 8, 3), 256, 0, stream>>>(
        x, Wq, bq, Wk, bk, Wv, bv, qb, kb, vt);
    attn_mfma_kernel<<<dim3(32, 32), 256, 0, stream>>>(qb, kb, vt, mask, out);
}

// Round 3
// 396.530 us; speedup vs baseline: 5.1523x; 1.5168x over previous
//
#include <hip/hip_runtime.h>

#define B_ 2
#define T_ 2048
#define C_ 1024
#define H_ 16
#define DH_ 64

typedef __attribute__((ext_vector_type(8))) short short8;   // 8 bf16 (4 VGPRs)
typedef __attribute__((ext_vector_type(4))) float f32x4;

__device__ __forceinline__ unsigned short f2bf(float f) {
    union { float f; unsigned u; } un; un.f = f;
    unsigned r = un.u + 0x7FFF + ((un.u >> 16) & 1);   // RNE
    return (unsigned short)(r >> 16);
}
__device__ __forceinline__ float bf2f(unsigned short u) {
    union { unsigned u; float f; } un; un.u = ((unsigned)u) << 16;
    return un.f;
}

__device__ __forceinline__ void gll16(const void* g, void* l) {
    __builtin_amdgcn_global_load_lds(
        (const __attribute__((address_space(1))) void*)g,
        (__attribute__((address_space(3))) void*)l, 16, 0, 0);
}

// ---------------------------------------------------------------------------
// Prep 1: split x (fp32) into xh + xl bf16 (x ~= xh + xl to ~2^-17 rel).
// ---------------------------------------------------------------------------
__global__ __launch_bounds__(256) void prep_x_kernel(
    const float* __restrict__ x,
    unsigned short* __restrict__ xh, unsigned short* __restrict__ xl)
{
    const size_t idx8 = ((size_t)blockIdx.x * 256 + threadIdx.x) * 8;
    float4 v0 = *(const float4*)(x + idx8);
    float4 v1 = *(const float4*)(x + idx8 + 4);
    float f[8] = {v0.x, v0.y, v0.z, v0.w, v1.x, v1.y, v1.z, v1.w};
    unsigned short h[8], l[8];
#pragma unroll
    for (int i = 0; i < 8; i++) {
        h[i] = f2bf(f[i]);
        l[i] = f2bf(f[i] - bf2f(h[i]));
    }
    *(uint4*)(xh + idx8) = *(const uint4*)h;
    *(uint4*)(xl + idx8) = *(const uint4*)l;
}

// ---------------------------------------------------------------------------
// Prep 2: transpose+convert W[z] (fp32 [K][N]) -> Wt[z] (bf16 [N][K]).
// ---------------------------------------------------------------------------
__global__ __launch_bounds__(256) void prep_w_kernel(
    const float* __restrict__ Wq, const float* __restrict__ Wk,
    const float* __restrict__ Wv, unsigned short* __restrict__ wt)
{
    __shared__ float tile[32][33];
    const int z = blockIdx.z;
    const float* __restrict__ W = (z == 0) ? Wq : (z == 1) ? Wk : Wv;
    unsigned short* __restrict__ wtz = wt + (size_t)z * C_ * C_;
    const int n0 = blockIdx.x * 32;
    const int k0 = blockIdx.y * 32;
    const int tx = threadIdx.x;      // 0..31
    const int ty = threadIdx.y;      // 0..7
#pragma unroll
    for (int j = 0; j < 4; j++)
        tile[ty + j * 8][tx] = W[(size_t)(k0 + ty + j * 8) * C_ + n0 + tx];
    __syncthreads();
#pragma unroll
    for (int j = 0; j < 4; j++)
        wtz[(size_t)(n0 + ty + j * 8) * C_ + k0 + tx] = f2bf(tile[tx][ty + j * 8]);
}

// ---------------------------------------------------------------------------
// Kernel 3: QKV projection as bf16 MFMA GEMM, split-precision x (xh + xl).
// z<2 : D[token][col] = (xh+xl) @ W   -> qb/kb [bh][T][64] bf16
// z==2: D[col][token] = (W^T x^T)     -> vt    [bh][64][T] bf16 (operand swap)
// 128x128 tile, BK=32, 4 waves (2x2), global_load_lds staging, 32 MFMA/wave/iter.
// ---------------------------------------------------------------------------
__global__ __launch_bounds__(256) void qkv_mfma_kernel(
    const unsigned short* __restrict__ xh, const unsigned short* __restrict__ xl,
    const unsigned short* __restrict__ wt,
    const float* __restrict__ bq, const float* __restrict__ bk,
    const float* __restrict__ bv,
    unsigned short* __restrict__ qb, unsigned short* __restrict__ kb,
    unsigned short* __restrict__ vt)
{
    __shared__ unsigned short sXh[128 * 32];
    __shared__ unsigned short sXl[128 * 32];
    __shared__ unsigned short sW [128 * 32];

    const int z = blockIdx.z;
    const float* __restrict__ bias = (z == 0) ? bq : (z == 1) ? bk : bv;
    const unsigned short* __restrict__ wtz = wt + (size_t)z * C_ * C_;

    const int tok0 = blockIdx.x * 128;
    const int col0 = blockIdx.y * 128;
    const int wv   = threadIdx.x >> 6;
    const int lane = threadIdx.x & 63;
    const int l15  = lane & 15;
    const int quad = lane >> 4;
    const int wm   = wv >> 1;       // 0..1
    const int wn   = wv & 1;        // 0..1
    const int lrow = lane >> 2;     // staging: row within 16-row chunk
    const int lc   = lane & 3;      // staging: 16B chunk within 64B row

    f32x4 acc[4][4];
#pragma unroll
    for (int i = 0; i < 4; i++)
#pragma unroll
        for (int j = 0; j < 4; j++) acc[i][j] = (f32x4){0.f, 0.f, 0.f, 0.f};

    int aoff[4], boff[4];
#pragma unroll
    for (int i = 0; i < 4; i++) {
        aoff[i] = (wm * 64 + i * 16 + l15) * 32 + quad * 8;
        boff[i] = (wn * 64 + i * 16 + l15) * 32 + quad * 8;
    }

    for (int k0 = 0; k0 < C_; k0 += 32) {
        __syncthreads();
        // stage 3 tiles (24 chunks of 16 rows); wave wv takes chunks wv+4s
#pragma unroll
        for (int s = 0; s < 6; ++s) {
            int c    = (s << 2) + wv;
            int tsel = c >> 3;
            int r0   = (c & 7) << 4;
            const unsigned short* src;
            unsigned short* dst;
            int rowg;
            if (tsel == 0)      { src = xh;  dst = sXh; rowg = tok0; }
            else if (tsel == 1) { src = xl;  dst = sXl; rowg = tok0; }
            else                { src = wtz; dst = sW;  rowg = col0; }
            const unsigned short* g = src + (size_t)(rowg + r0 + lrow) * C_ + k0 + lc * 8;
            gll16(g, dst + r0 * 32);
        }
        __syncthreads();

        if (z < 2) {
            short8 ah[4], al_[4];
#pragma unroll
            for (int i = 0; i < 4; i++) {
                ah[i]  = *(const short8*)&sXh[aoff[i]];
                al_[i] = *(const short8*)&sXl[aoff[i]];
            }
#pragma unroll
            for (int j = 0; j < 4; j++) {
                short8 bw = *(const short8*)&sW[boff[j]];
#pragma unroll
                for (int i = 0; i < 4; i++) {
                    acc[i][j] = __builtin_amdgcn_mfma_f32_16x16x32_bf16(ah[i],  bw, acc[i][j], 0, 0, 0);
                    acc[i][j] = __builtin_amdgcn_mfma_f32_16x16x32_bf16(al_[i], bw, acc[i][j], 0, 0, 0);
                }
            }
        } else {
            short8 aw[4];
#pragma unroll
            for (int i = 0; i < 4; i++) aw[i] = *(const short8*)&sW[aoff[i]];
#pragma unroll
            for (int j = 0; j < 4; j++) {
                short8 bh_ = *(const short8*)&sXh[boff[j]];
                short8 bl_ = *(const short8*)&sXl[boff[j]];
#pragma unroll
                for (int i = 0; i < 4; i++) {
                    acc[i][j] = __builtin_amdgcn_mfma_f32_16x16x32_bf16(aw[i], bh_, acc[i][j], 0, 0, 0);
                    acc[i][j] = __builtin_amdgcn_mfma_f32_16x16x32_bf16(aw[i], bl_, acc[i][j], 0, 0, 0);
                }
            }
        }
    }

    // ---- epilogue ----
    if (z < 2) {
        unsigned short* outp = (z == 0) ? qb : kb;
#pragma unroll
        for (int j = 0; j < 4; j++) {
            int col = col0 + wn * 64 + j * 16 + l15;
            int h = col >> 6, d = col & 63;
            float bs = bias[col];
#pragma unroll
            for (int i = 0; i < 4; i++) {
#pragma unroll
                for (int r = 0; r < 4; r++) {
                    int tok = tok0 + wm * 64 + i * 16 + quad * 4 + r;
                    int bidx = tok >> 11, t = tok & (T_ - 1);
                    outp[((size_t)(bidx * H_ + h) * T_ + t) * DH_ + d] =
                        f2bf(acc[i][j][r] + bs);
                }
            }
        }
    } else {
#pragma unroll
        for (int i = 0; i < 4; i++) {
#pragma unroll
            for (int r = 0; r < 4; r++) {
                int col = col0 + wm * 64 + i * 16 + quad * 4 + r;
                int h = col >> 6, d = col & 63;
                float bs = bias[col];
#pragma unroll
                for (int j = 0; j < 4; j++) {
                    int tok = tok0 + wn * 64 + j * 16 + l15;
                    int bidx = tok >> 11, t = tok & (T_ - 1);
                    vt[((size_t)(bidx * H_ + h) * DH_ + d) * T_ + t] =
                        f2bf(acc[i][j][r] + bs);
                }
            }
        }
    }
}

// ---------------------------------------------------------------------------
// Kernel 4: MFMA flash attention (unchanged from R2).
// ---------------------------------------------------------------------------
__global__ __launch_bounds__(256) void attn_mfma_kernel(
    const unsigned short* __restrict__ qb,
    const unsigned short* __restrict__ kb,
    const unsigned short* __restrict__ vt,
    const int* __restrict__ mask,
    float* __restrict__ out)
{
    __shared__ unsigned short Pb[4][16][72];

    const int bh   = blockIdx.y;
    const int b    = bh >> 4;
    const int h    = bh & 15;
    const int wv   = threadIdx.x >> 6;
    const int lane = threadIdx.x & 63;
    const int l15  = lane & 15;
    const int quad = lane >> 4;
    const int q0   = blockIdx.x * 64 + wv * 16;

    const int* __restrict__ mrow = mask + b * T_;

    const unsigned short* qbase = qb + ((size_t)bh * T_ + q0 + l15) * DH_ + quad * 8;
    short8 qf0 = *(const short8*)(qbase);
    short8 qf1 = *(const short8*)(qbase + 32);

    const unsigned short* kbh = kb + (size_t)bh * T_ * DH_;
    const unsigned short* vbh = vt + (size_t)bh * DH_ * T_;

    f32x4 o[4];
#pragma unroll
    for (int n = 0; n < 4; n++) o[n] = (f32x4){0.f, 0.f, 0.f, 0.f};
    float lsum[4] = {0.f, 0.f, 0.f, 0.f};

    for (int kt = 0; kt < 32; ++kt) {
        const int kbase = kt * 64;

        f32x4 s[4];
#pragma unroll
        for (int n = 0; n < 4; ++n) {
            const unsigned short* kptr = kbh + (size_t)(kbase + n * 16 + l15) * DH_ + quad * 8;
            short8 kf0 = *(const short8*)(kptr);
            short8 kf1 = *(const short8*)(kptr + 32);
            f32x4 acc = (f32x4){0.f, 0.f, 0.f, 0.f};
            acc = __builtin_amdgcn_mfma_f32_16x16x32_bf16(qf0, kf0, acc, 0, 0, 0);
            acc = __builtin_amdgcn_mfma_f32_16x16x32_bf16(qf1, kf1, acc, 0, 0, 0);
            s[n] = acc;
        }

#pragma unroll
        for (int n = 0; n < 4; ++n) {
            float km = (mrow[kbase + n * 16 + l15] != 0) ? 1.f : 0.f;
#pragma unroll
            for (int r = 0; r < 4; ++r) {
                float sv = fminf(s[n][r] * 0.125f, 60.f);
                float p = __expf(sv) * km;
                lsum[r] += p;
                Pb[wv][quad * 4 + r][n * 16 + l15] = f2bf(p);
            }
        }

        const unsigned short* prow = &Pb[wv][l15][quad * 8];
        short8 pf0 = *(const short8*)(prow);
        short8 pf1 = *(const short8*)(prow + 32);

#pragma unroll
        for (int n = 0; n < 4; ++n) {
            const unsigned short* vptr = vbh + (size_t)(n * 16 + l15) * T_ + kbase + quad * 8;
            short8 vf0 = *(const short8*)(vptr);
            short8 vf1 = *(const short8*)(vptr + 32);
            o[n] = __builtin_amdgcn_mfma_f32_16x16x32_bf16(pf0, vf0, o[n], 0, 0, 0);
            o[n] = __builtin_amdgcn_mfma_f32_16x16x32_bf16(pf1, vf1, o[n], 0, 0, 0);
        }
    }

#pragma unroll
    for (int r = 0; r < 4; ++r) {
#pragma unroll
        for (int off = 1; off < 16; off <<= 1)
            lsum[r] += __shfl_xor(lsum[r], off, 64);
    }

    float inv[4];
#pragma unroll
    for (int r = 0; r < 4; ++r) {
        int qrow = q0 + quad * 4 + r;
        bool valid = (mrow[qrow] != 0) && (lsum[r] > 0.f);
        inv[r] = valid ? (1.0f / lsum[r]) : 0.f;
    }

#pragma unroll
    for (int r = 0; r < 4; ++r) {
        int qrow = q0 + quad * 4 + r;
        float* orow = out + ((size_t)(b * T_ + qrow)) * C_ + h * DH_;
#pragma unroll
        for (int n = 0; n < 4; ++n)
            orow[n * 16 + l15] = o[n][r] * inv[r];
    }
}

// ---------------------------------------------------------------------------
extern "C" void kernel_launch(void* const* d_in, const int* in_sizes, int n_in,
                              void* d_out, int out_size, void* d_ws, size_t ws_size,
                              hipStream_t stream)
{
    (void)in_sizes; (void)n_in; (void)out_size; (void)ws_size;
    const float* x  = (const float*)d_in[0];
    const float* Wq = (const float*)d_in[1];
    const float* bq = (const float*)d_in[2];
    const float* Wk = (const float*)d_in[3];
    const float* bk = (const float*)d_in[4];
    const float* Wv = (const float*)d_in[5];
    const float* bv = (const float*)d_in[6];
    const int* mask = (const int*)d_in[7];
    float* out = (float*)d_out;

    const size_t NX = (size_t)B_ * T_ * C_;     // 4 Mi
    unsigned short* xh = (unsigned short*)d_ws;  // 8 MB
    unsigned short* xl = xh + NX;                // 8 MB
    unsigned short* wt = xl + NX;                // 6 MB (3 x 1024 x 1024)
    unsigned short* qb = wt + (size_t)3 * C_ * C_;  // 8 MB
    unsigned short* kb = qb + NX;                // 8 MB
    unsigned short* vt = kb + NX;                // 8 MB

    prep_x_kernel<<<2048, 256, 0, stream>>>(x, xh, xl);
    prep_w_kernel<<<dim3(32, 32, 3), dim3(32, 8), 0, stream>>>(Wq, Wk, Wv, wt);
    qkv_mfma_kernel<<<dim3(32, 8, 3), 256, 0, stream>>>(
        xh, xl, wt, bq, bk, bv, qb, kb, vt);
    attn_mfma_kernel<<<dim3(32, 32), 256, 0, stream>>>(qb, kb, vt, mask, out);
}

// Round 4
// 217.780 us; speedup vs baseline: 9.3812x; 1.8208x over previous
//
#include <hip/hip_runtime.h>

#define B_ 2
#define T_ 2048
#define C_ 1024
#define H_ 16
#define DH_ 64

typedef __attribute__((ext_vector_type(8))) short short8;   // 8 bf16 (4 VGPRs)
typedef __attribute__((ext_vector_type(4))) float f32x4;

__device__ __forceinline__ unsigned short f2bf(float f) {
    union { float f; unsigned u; } un; un.f = f;
    unsigned r = un.u + 0x7FFF + ((un.u >> 16) & 1);   // RNE
    return (unsigned short)(r >> 16);
}
__device__ __forceinline__ float bf2f(unsigned short u) {
    union { unsigned u; float f; } un; un.u = ((unsigned)u) << 16;
    return un.f;
}

__device__ __forceinline__ void gll16(const void* g, void* l) {
    __builtin_amdgcn_global_load_lds(
        (const __attribute__((address_space(1))) void*)g,
        (__attribute__((address_space(3))) void*)l, 16, 0, 0);
}

// ---------------------------------------------------------------------------
// Prep 1: split x (fp32) into xh + xl bf16.
// ---------------------------------------------------------------------------
__global__ __launch_bounds__(256) void prep_x_kernel(
    const float* __restrict__ x,
    unsigned short* __restrict__ xh, unsigned short* __restrict__ xl)
{
    const size_t idx8 = ((size_t)blockIdx.x * 256 + threadIdx.x) * 8;
    float4 v0 = *(const float4*)(x + idx8);
    float4 v1 = *(const float4*)(x + idx8 + 4);
    float f[8] = {v0.x, v0.y, v0.z, v0.w, v1.x, v1.y, v1.z, v1.w};
    unsigned short h[8], l[8];
#pragma unroll
    for (int i = 0; i < 8; i++) {
        h[i] = f2bf(f[i]);
        l[i] = f2bf(f[i] - bf2f(h[i]));
    }
    *(uint4*)(xh + idx8) = *(const uint4*)h;
    *(uint4*)(xl + idx8) = *(const uint4*)l;
}

// ---------------------------------------------------------------------------
// Prep 2: transpose+convert W[z] (fp32 [K][N]) -> Wt[z] (bf16 [N][K]).
// ---------------------------------------------------------------------------
__global__ __launch_bounds__(256) void prep_w_kernel(
    const float* __restrict__ Wq, const float* __restrict__ Wk,
    const float* __restrict__ Wv, unsigned short* __restrict__ wt)
{
    __shared__ float tile[32][33];
    const int z = blockIdx.z;
    const float* __restrict__ W = (z == 0) ? Wq : (z == 1) ? Wk : Wv;
    unsigned short* __restrict__ wtz = wt + (size_t)z * C_ * C_;
    const int n0 = blockIdx.x * 32;
    const int k0 = blockIdx.y * 32;
    const int tx = threadIdx.x;
    const int ty = threadIdx.y;
#pragma unroll
    for (int j = 0; j < 4; j++)
        tile[ty + j * 8][tx] = W[(size_t)(k0 + ty + j * 8) * C_ + n0 + tx];
    __syncthreads();
#pragma unroll
    for (int j = 0; j < 4; j++)
        wtz[(size_t)(n0 + ty + j * 8) * C_ + k0 + tx] = f2bf(tile[tx][ty + j * 8]);
}

// ---------------------------------------------------------------------------
// Prep 3: mask (int) -> bf16 {0,1} vector for the l-MFMA.
// ---------------------------------------------------------------------------
__global__ __launch_bounds__(256) void prep_mask_kernel(
    const int* __restrict__ mask, unsigned short* __restrict__ mb)
{
    int i = blockIdx.x * 256 + threadIdx.x;          // B_*T_ = 4096
    mb[i] = (mask[i] != 0) ? (unsigned short)0x3F80 : (unsigned short)0;
}

// ---------------------------------------------------------------------------
// Kernel: QKV projection, bf16 MFMA, split-precision x. (as R3; z==2 now
// multiplies V rows by the key mask so attention numerator needs no masking)
// ---------------------------------------------------------------------------
__global__ __launch_bounds__(256) void qkv_mfma_kernel(
    const unsigned short* __restrict__ xh, const unsigned short* __restrict__ xl,
    const unsigned short* __restrict__ wt,
    const float* __restrict__ bq, const float* __restrict__ bk,
    const float* __restrict__ bv, const int* __restrict__ maskp,
    unsigned short* __restrict__ qb, unsigned short* __restrict__ kb,
    unsigned short* __restrict__ vt)
{
    __shared__ unsigned short sXh[128 * 32];
    __shared__ unsigned short sXl[128 * 32];
    __shared__ unsigned short sW [128 * 32];

    const int z = blockIdx.z;
    const float* __restrict__ bias = (z == 0) ? bq : (z == 1) ? bk : bv;
    const unsigned short* __restrict__ wtz = wt + (size_t)z * C_ * C_;

    const int tok0 = blockIdx.x * 128;
    const int col0 = blockIdx.y * 128;
    const int wv   = threadIdx.x >> 6;
    const int lane = threadIdx.x & 63;
    const int l15  = lane & 15;
    const int quad = lane >> 4;
    const int wm   = wv >> 1;
    const int wn   = wv & 1;
    const int lrow = lane >> 2;
    const int lc   = lane & 3;

    f32x4 acc[4][4];
#pragma unroll
    for (int i = 0; i < 4; i++)
#pragma unroll
        for (int j = 0; j < 4; j++) acc[i][j] = (f32x4){0.f, 0.f, 0.f, 0.f};

    int aoff[4], boff[4];
#pragma unroll
    for (int i = 0; i < 4; i++) {
        aoff[i] = (wm * 64 + i * 16 + l15) * 32 + quad * 8;
        boff[i] = (wn * 64 + i * 16 + l15) * 32 + quad * 8;
    }

    for (int k0 = 0; k0 < C_; k0 += 32) {
        __syncthreads();
#pragma unroll
        for (int s = 0; s < 6; ++s) {
            int c    = (s << 2) + wv;
            int tsel = c >> 3;
            int r0   = (c & 7) << 4;
            const unsigned short* src;
            unsigned short* dst;
            int rowg;
            if (tsel == 0)      { src = xh;  dst = sXh; rowg = tok0; }
            else if (tsel == 1) { src = xl;  dst = sXl; rowg = tok0; }
            else                { src = wtz; dst = sW;  rowg = col0; }
            const unsigned short* g = src + (size_t)(rowg + r0 + lrow) * C_ + k0 + lc * 8;
            gll16(g, dst + r0 * 32);
        }
        __syncthreads();

        if (z < 2) {
            short8 ah[4], al_[4];
#pragma unroll
            for (int i = 0; i < 4; i++) {
                ah[i]  = *(const short8*)&sXh[aoff[i]];
                al_[i] = *(const short8*)&sXl[aoff[i]];
            }
#pragma unroll
            for (int j = 0; j < 4; j++) {
                short8 bw = *(const short8*)&sW[boff[j]];
#pragma unroll
                for (int i = 0; i < 4; i++) {
                    acc[i][j] = __builtin_amdgcn_mfma_f32_16x16x32_bf16(ah[i],  bw, acc[i][j], 0, 0, 0);
                    acc[i][j] = __builtin_amdgcn_mfma_f32_16x16x32_bf16(al_[i], bw, acc[i][j], 0, 0, 0);
                }
            }
        } else {
            short8 aw[4];
#pragma unroll
            for (int i = 0; i < 4; i++) aw[i] = *(const short8*)&sW[aoff[i]];
#pragma unroll
            for (int j = 0; j < 4; j++) {
                short8 bh_ = *(const short8*)&sXh[boff[j]];
                short8 bl_ = *(const short8*)&sXl[boff[j]];
#pragma unroll
                for (int i = 0; i < 4; i++) {
                    acc[i][j] = __builtin_amdgcn_mfma_f32_16x16x32_bf16(aw[i], bh_, acc[i][j], 0, 0, 0);
                    acc[i][j] = __builtin_amdgcn_mfma_f32_16x16x32_bf16(aw[i], bl_, acc[i][j], 0, 0, 0);
                }
            }
        }
    }

    if (z < 2) {
        unsigned short* outp = (z == 0) ? qb : kb;
#pragma unroll
        for (int j = 0; j < 4; j++) {
            int col = col0 + wn * 64 + j * 16 + l15;
            int h = col >> 6, d = col & 63;
            float bs = bias[col];
#pragma unroll
            for (int i = 0; i < 4; i++) {
#pragma unroll
                for (int r = 0; r < 4; r++) {
                    int tok = tok0 + wm * 64 + i * 16 + quad * 4 + r;
                    int bidx = tok >> 11, t = tok & (T_ - 1);
                    outp[((size_t)(bidx * H_ + h) * T_ + t) * DH_ + d] =
                        f2bf(acc[i][j][r] + bs);
                }
            }
        }
    } else {
        float mv4[4]; int bidx4[4], t4[4];
#pragma unroll
        for (int j = 0; j < 4; j++) {
            int tok = tok0 + wn * 64 + j * 16 + l15;
            bidx4[j] = tok >> 11; t4[j] = tok & (T_ - 1);
            mv4[j] = (maskp[bidx4[j] * T_ + t4[j]] != 0) ? 1.f : 0.f;
        }
#pragma unroll
        for (int i = 0; i < 4; i++) {
#pragma unroll
            for (int r = 0; r < 4; r++) {
                int col = col0 + wm * 64 + i * 16 + quad * 4 + r;
                int h = col >> 6, d = col & 63;
                float bs = bias[col];
#pragma unroll
                for (int j = 0; j < 4; j++) {
                    vt[((size_t)(bidx4[j] * H_ + h) * DH_ + d) * T_ + t4[j]] =
                        f2bf((acc[i][j][r] + bs) * mv4[j]);
                }
            }
        }
    }
}

// ---------------------------------------------------------------------------
// Attention: S-transposed MFMA flash, LDS-staged K/V (double-buffered,
// global_load_lds, XOR chunk swizzle), mask folded into V + l via MFMA.
// Wave = 32 q rows (2 qtiles of 16); block = 4 waves = 128 q of one (b,h).
// ---------------------------------------------------------------------------
__global__ __launch_bounds__(256) void attn_mfma_kernel(
    const unsigned short* __restrict__ qb,  // [32][2048][64] bf16
    const unsigned short* __restrict__ kb,  // [32][2048][64] bf16
    const unsigned short* __restrict__ vt,  // [32][64][2048] bf16 (mask-zeroed)
    const int* __restrict__ mask,           // [2][2048]
    const unsigned short* __restrict__ mb,  // [2][2048] bf16 {0,1}
    float* __restrict__ out)                // [2][2048][1024]
{
    __shared__ unsigned short Ks[2][64 * 64];   // [buf][key][dh] swizzled
    __shared__ unsigned short Vs[2][64 * 64];   // [buf][dh][key] swizzled
    __shared__ unsigned short Ps[4][2][16 * 64]; // [wave][qtile][q][key] swizzled

    const int bh   = blockIdx.y;
    const int b    = bh >> 4;
    const int h    = bh & 15;
    const int wv   = threadIdx.x >> 6;
    const int lane = threadIdx.x & 63;
    const int l15  = lane & 15;
    const int quad = lane >> 4;
    const int l7   = l15 & 7;
    const int q0w  = blockIdx.x * 128 + wv * 32;

    const unsigned short* kbh = kb + (size_t)bh * T_ * DH_;
    const unsigned short* vbh = vt + (size_t)bh * DH_ * T_;
    const unsigned short* mbb = mb + b * T_;
    const int* __restrict__ mrow = mask + b * T_;

    // Q fragments (B operand): Q[q0w+qt*16+l15][c*32 + quad*8 ..]
    short8 qf[2][2];
#pragma unroll
    for (int qt = 0; qt < 2; ++qt)
#pragma unroll
        for (int c = 0; c < 2; ++c)
            qf[qt][c] = *(const short8*)(qb + ((size_t)bh * T_ + q0w + qt * 16 + l15) * DH_
                                         + c * 32 + quad * 8);

    f32x4 o[2][4];
#pragma unroll
    for (int qt = 0; qt < 2; ++qt)
#pragma unroll
        for (int n = 0; n < 4; ++n) o[qt][n] = (f32x4){0.f, 0.f, 0.f, 0.f};
    f32x4 lacc[2];
    lacc[0] = (f32x4){0.f, 0.f, 0.f, 0.f};
    lacc[1] = (f32x4){0.f, 0.f, 0.f, 0.f};

    // staging lane constants: slot(row, chunk=lane&7) <- global(row, (lane&7)^(lane>>3))
    const int lrow = lane >> 3;
    const int gch  = (lane & 7) ^ lrow;

    // ---- prologue: stage tile 0 into buf 0 ----
#pragma unroll
    for (int s = 0; s < 4; ++s) {
        int j  = (wv << 2) + s;     // 0..15
        int rb = j & 7;
        if (j < 8) {
            gll16(kbh + (size_t)(0 + rb * 8 + lrow) * DH_ + gch * 8, &Ks[0][rb * 512]);
        } else {
            gll16(vbh + (size_t)(rb * 8 + lrow) * T_ + 0 + gch * 8, &Vs[0][rb * 512]);
        }
    }

    for (int kt = 0; kt < 32; ++kt) {
        const int cur   = kt & 1;
        const int kbase = kt * 64;
        __syncthreads();                 // buf[cur] staging complete; prev iter done

        if (kt < 31) {
            const int nb = kbase + 64;
#pragma unroll
            for (int s = 0; s < 4; ++s) {
                int j  = (wv << 2) + s;
                int rb = j & 7;
                if (j < 8) {
                    gll16(kbh + (size_t)(nb + rb * 8 + lrow) * DH_ + gch * 8,
                          &Ks[cur ^ 1][rb * 512]);
                } else {
                    gll16(vbh + (size_t)(rb * 8 + lrow) * T_ + nb + gch * 8,
                          &Vs[cur ^ 1][rb * 512]);
                }
            }
        }

        const unsigned short* Kc = &Ks[cur][0];
        const unsigned short* Vc = &Vs[cur][0];

        // K fragments (A operand): K[ktile*16+l15][c*32+quad*8..], swizzled
        short8 kf[4][2];
#pragma unroll
        for (int ktile = 0; ktile < 4; ++ktile)
#pragma unroll
            for (int c = 0; c < 2; ++c)
                kf[ktile][c] = *(const short8*)(Kc + (ktile * 16 + l15) * 64
                                                + (((c * 4 + quad) ^ l7) * 8));

        // mask B-fragments for the l-MFMA (row n=0 only)
        short8 bmf[2];
#pragma unroll
        for (int kc = 0; kc < 2; ++kc) {
            short8 mv = *(const short8*)(mbb + kbase + kc * 32 + quad * 8);
            bmf[kc] = (l15 == 0) ? mv : (short8)0;
        }

#pragma unroll
        for (int qt = 0; qt < 2; ++qt) {
            unsigned short* Pq = &Ps[wv][qt][0];

            // ---- S^T = K Q^T, exp, pack, write row-strips of P[q][key] ----
#pragma unroll
            for (int ktile = 0; ktile < 4; ++ktile) {
                f32x4 st = (f32x4){0.f, 0.f, 0.f, 0.f};
                st = __builtin_amdgcn_mfma_f32_16x16x32_bf16(kf[ktile][0], qf[qt][0], st, 0, 0, 0);
                st = __builtin_amdgcn_mfma_f32_16x16x32_bf16(kf[ktile][1], qf[qt][1], st, 0, 0, 0);
                unsigned u[4];
#pragma unroll
                for (int r = 0; r < 4; ++r)
                    u[r] = __float_as_uint(__builtin_amdgcn_exp2f(st[r] * 0.18033688011112042f));
                uint2 pk;
                pk.x = __builtin_amdgcn_perm(u[1], u[0], 0x07060302u);   // bf16-trunc pair
                pk.y = __builtin_amdgcn_perm(u[3], u[2], 0x07060302u);
                // keys ktile*16 + quad*4 + (0..3) at q=l15
                *(uint2*)(Pq + l15 * 64 + (((ktile * 2 + (quad >> 1)) ^ l7) * 8)
                          + (quad & 1) * 4) = pk;
            }

            // ---- read P as A-fragments (same-wave DS ordering) ----
            short8 pf[2];
#pragma unroll
            for (int kc = 0; kc < 2; ++kc)
                pf[kc] = *(const short8*)(Pq + l15 * 64 + (((kc * 4 + quad) ^ l7) * 8));

            // ---- l += P . maskvec (col 0 of D) ----
            lacc[qt] = __builtin_amdgcn_mfma_f32_16x16x32_bf16(pf[0], bmf[0], lacc[qt], 0, 0, 0);
            lacc[qt] = __builtin_amdgcn_mfma_f32_16x16x32_bf16(pf[1], bmf[1], lacc[qt], 0, 0, 0);

            // ---- O += P V (V pre-masked) ----
#pragma unroll
            for (int n = 0; n < 4; ++n) {
#pragma unroll
                for (int kc = 0; kc < 2; ++kc) {
                    short8 vf = *(const short8*)(Vc + (n * 16 + l15) * 64
                                                 + (((kc * 4 + quad) ^ l7) * 8));
                    o[qt][n] = __builtin_amdgcn_mfma_f32_16x16x32_bf16(pf[kc], vf, o[qt][n], 0, 0, 0);
                }
            }
        }
    }

    // ---- epilogue: l lives in D col 0 (lanes l15==0), rows quad*4+r ----
#pragma unroll
    for (int qt = 0; qt < 2; ++qt) {
#pragma unroll
        for (int r = 0; r < 4; ++r) {
            float lv = __shfl(lacc[qt][r], quad << 4, 64);
            int q = q0w + qt * 16 + quad * 4 + r;
            float iv = (mrow[q] != 0 && lv > 0.f) ? (1.0f / lv) : 0.f;
            float* orow = out + ((size_t)(b * T_ + q)) * C_ + h * DH_;
#pragma unroll
            for (int n = 0; n < 4; ++n)
                orow[n * 16 + l15] = o[qt][n][r] * iv;
        }
    }
}

// ---------------------------------------------------------------------------
extern "C" void kernel_launch(void* const* d_in, const int* in_sizes, int n_in,
                              void* d_out, int out_size, void* d_ws, size_t ws_size,
                              hipStream_t stream)
{
    (void)in_sizes; (void)n_in; (void)out_size; (void)ws_size;
    const float* x  = (const float*)d_in[0];
    const float* Wq = (const float*)d_in[1];
    const float* bq = (const float*)d_in[2];
    const float* Wk = (const float*)d_in[3];
    const float* bk = (const float*)d_in[4];
    const float* Wv = (const float*)d_in[5];
    const float* bv = (const float*)d_in[6];
    const int* mask = (const int*)d_in[7];
    float* out = (float*)d_out;

    const size_t NX = (size_t)B_ * T_ * C_;          // 4 Mi
    unsigned short* xh = (unsigned short*)d_ws;       // 8 MB
    unsigned short* xl = xh + NX;                     // 8 MB
    unsigned short* wt = xl + NX;                     // 6 MB
    unsigned short* qb = wt + (size_t)3 * C_ * C_;    // 8 MB
    unsigned short* kb = qb + NX;                     // 8 MB
    unsigned short* vt = kb + NX;                     // 8 MB
    unsigned short* mb = vt + NX;                     // 8 KB

    prep_x_kernel<<<2048, 256, 0, stream>>>(x, xh, xl);
    prep_mask_kernel<<<16, 256, 0, stream>>>(mask, mb);
    prep_w_kernel<<<dim3(32, 32, 3), dim3(32, 8), 0, stream>>>(Wq, Wk, Wv, wt);
    qkv_mfma_kernel<<<dim3(32, 8, 3), 256, 0, stream>>>(
        xh, xl, wt, bq, bk, bv, mask, qb, kb, vt);
    attn_mfma_kernel<<<dim3(16, 32), 256, 0, stream>>>(qb, kb, vt, mask, mb, out);
}

// Round 5
// 178.760 us; speedup vs baseline: 11.4289x; 1.2183x over previous
//
#include <hip/hip_runtime.h>

#define B_ 2
#define T_ 2048
#define C_ 1024
#define H_ 16
#define DH_ 64

typedef __attribute__((ext_vector_type(8))) _Float16 half8;  // 8 f16 (4 VGPRs)
typedef __attribute__((ext_vector_type(4))) float f32x4;

__device__ __forceinline__ unsigned short f2h(float f) {
    union { _Float16 h; unsigned short u; } cv; cv.h = (_Float16)f; return cv.u;
}

__device__ __forceinline__ void gll16(const void* g, void* l) {
    __builtin_amdgcn_global_load_lds(
        (const __attribute__((address_space(1))) void*)g,
        (__attribute__((address_space(3))) void*)l, 16, 0, 0);
}

// ---------------------------------------------------------------------------
// Prep 1: x fp32 -> fp16; block 0 also emits the fp16 {0,1} mask vector.
// ---------------------------------------------------------------------------
__global__ __launch_bounds__(256) void prep_x_kernel(
    const float* __restrict__ x, unsigned short* __restrict__ xf,
    const int* __restrict__ mask, unsigned short* __restrict__ mb)
{
    const size_t idx8 = ((size_t)blockIdx.x * 256 + threadIdx.x) * 8;
    float4 v0 = *(const float4*)(x + idx8);
    float4 v1 = *(const float4*)(x + idx8 + 4);
    float f[8] = {v0.x, v0.y, v0.z, v0.w, v1.x, v1.y, v1.z, v1.w};
    unsigned short h[8];
#pragma unroll
    for (int i = 0; i < 8; i++) h[i] = f2h(f[i]);
    *(uint4*)(xf + idx8) = *(const uint4*)h;

    if (blockIdx.x == 0) {
#pragma unroll
        for (int j = 0; j < 16; j++) {
            int i = threadIdx.x * 16 + j;           // covers B_*T_ = 4096
            mb[i] = (mask[i] != 0) ? (unsigned short)0x3C00 : (unsigned short)0;
        }
    }
}

// ---------------------------------------------------------------------------
// Prep 2: transpose+convert W[z] (fp32 [K][N]) -> Wt[z] (fp16 [N][K]).
// ---------------------------------------------------------------------------
__global__ __launch_bounds__(256) void prep_w_kernel(
    const float* __restrict__ Wq, const float* __restrict__ Wk,
    const float* __restrict__ Wv, unsigned short* __restrict__ wt)
{
    __shared__ float tile[32][33];
    const int z = blockIdx.z;
    const float* __restrict__ W = (z == 0) ? Wq : (z == 1) ? Wk : Wv;
    unsigned short* __restrict__ wtz = wt + (size_t)z * C_ * C_;
    const int n0 = blockIdx.x * 32;
    const int k0 = blockIdx.y * 32;
    const int tx = threadIdx.x;
    const int ty = threadIdx.y;
#pragma unroll
    for (int j = 0; j < 4; j++)
        tile[ty + j * 8][tx] = W[(size_t)(k0 + ty + j * 8) * C_ + n0 + tx];
    __syncthreads();
#pragma unroll
    for (int j = 0; j < 4; j++)
        wtz[(size_t)(n0 + ty + j * 8) * C_ + k0 + tx] = f2h(tile[tx][ty + j * 8]);
}

// ---------------------------------------------------------------------------
// QKV projection: single-pass fp16 MFMA GEMM. 128x128 tile, BK=64, 4 waves
// (2x2, 64x64 each), XOR-swizzled LDS (conflict-free b128 frag reads).
// z<2 : A=x, B=W -> D[token][col] -> qb/kb [bh][T][64] fp16
// z==2: A=W, B=x -> D[col][token] -> vt [bh][64][T] fp16, mask-zeroed
// ---------------------------------------------------------------------------
__global__ __launch_bounds__(256) void qkv_mfma_kernel(
    const unsigned short* __restrict__ xf, const unsigned short* __restrict__ wt,
    const float* __restrict__ bq, const float* __restrict__ bk,
    const float* __restrict__ bv, const int* __restrict__ maskp,
    unsigned short* __restrict__ qb, unsigned short* __restrict__ kb,
    unsigned short* __restrict__ vt)
{
    __shared__ unsigned short sX[128 * 64];   // [row][k] swizzled, 16 KB
    __shared__ unsigned short sW[128 * 64];

    const int z = blockIdx.z;
    const float* __restrict__ bias = (z == 0) ? bq : (z == 1) ? bk : bv;
    const unsigned short* __restrict__ wtz = wt + (size_t)z * C_ * C_;

    const int tok0 = blockIdx.x * 128;
    const int col0 = blockIdx.y * 128;
    const int wv    = threadIdx.x >> 6;
    const int lane  = threadIdx.x & 63;
    const int l15   = lane & 15;
    const int quad  = lane >> 4;
    const int l7    = l15 & 7;
    const int wm    = wv >> 1;
    const int wn    = wv & 1;
    const int lrow8 = lane >> 3;           // staging: row within 8-row group
    const int gch   = (lane & 7) ^ lrow8;  // staging: swizzled global chunk

    f32x4 acc[4][4];
#pragma unroll
    for (int i = 0; i < 4; i++)
#pragma unroll
        for (int j = 0; j < 4; j++) acc[i][j] = (f32x4){0.f, 0.f, 0.f, 0.f};

    // fragment element offsets: row*64 + ((s*4+quad)^l7)*8
    int aoff[4][2], boff[4][2];
#pragma unroll
    for (int i = 0; i < 4; i++)
#pragma unroll
        for (int s = 0; s < 2; s++) {
            aoff[i][s] = (wm * 64 + i * 16 + l15) * 64 + (((s * 4 + quad) ^ l7) * 8);
            boff[i][s] = (wn * 64 + i * 16 + l15) * 64 + (((s * 4 + quad) ^ l7) * 8);
        }

    const unsigned short* Abuf = (z < 2) ? sX : sW;
    const unsigned short* Bbuf = (z < 2) ? sW : sX;

    for (int k0 = 0; k0 < C_; k0 += 64) {
        __syncthreads();
        // stage 32 KB: 32 groups of (8 rows x 128 B); wave wv takes g = wv+4s
#pragma unroll
        for (int s = 0; s < 8; ++s) {
            int g    = (s << 2) + wv;
            int tsel = g >> 4;
            int r0   = (g & 15) << 3;
            const unsigned short* src = tsel ? wtz : xf;
            unsigned short*       dst = tsel ? sW  : sX;
            int rowg = tsel ? col0 : tok0;
            gll16(src + (size_t)(rowg + r0 + lrow8) * C_ + k0 + gch * 8,
                  dst + r0 * 64);
        }
        __syncthreads();

        half8 af[4][2], bf_[4][2];
#pragma unroll
        for (int i = 0; i < 4; i++)
#pragma unroll
            for (int s = 0; s < 2; s++) {
                af[i][s]  = *(const half8*)&Abuf[aoff[i][s]];
                bf_[i][s] = *(const half8*)&Bbuf[boff[i][s]];
            }
#pragma unroll
        for (int s = 0; s < 2; s++)
#pragma unroll
            for (int j = 0; j < 4; j++)
#pragma unroll
                for (int i = 0; i < 4; i++)
                    acc[i][j] = __builtin_amdgcn_mfma_f32_16x16x32_f16(
                        af[i][s], bf_[j][s], acc[i][j], 0, 0, 0);
    }

    if (z < 2) {
        unsigned short* outp = (z == 0) ? qb : kb;
#pragma unroll
        for (int j = 0; j < 4; j++) {
            int col = col0 + wn * 64 + j * 16 + l15;
            int h = col >> 6, d = col & 63;
            float bs = bias[col];
#pragma unroll
            for (int i = 0; i < 4; i++) {
#pragma unroll
                for (int r = 0; r < 4; r++) {
                    int tok = tok0 + wm * 64 + i * 16 + quad * 4 + r;
                    int bidx = tok >> 11, t = tok & (T_ - 1);
                    outp[((size_t)(bidx * H_ + h) * T_ + t) * DH_ + d] =
                        f2h(acc[i][j][r] + bs);
                }
            }
        }
    } else {
        float mv4[4]; int bidx4[4], t4[4];
#pragma unroll
        for (int j = 0; j < 4; j++) {
            int tok = tok0 + wn * 64 + j * 16 + l15;
            bidx4[j] = tok >> 11; t4[j] = tok & (T_ - 1);
            mv4[j] = (maskp[bidx4[j] * T_ + t4[j]] != 0) ? 1.f : 0.f;
        }
#pragma unroll
        for (int i = 0; i < 4; i++) {
#pragma unroll
            for (int r = 0; r < 4; r++) {
                int col = col0 + wm * 64 + i * 16 + quad * 4 + r;
                int h = col >> 6, d = col & 63;
                float bs = bias[col];
#pragma unroll
                for (int j = 0; j < 4; j++) {
                    vt[((size_t)(bidx4[j] * H_ + h) * DH_ + d) * T_ + t4[j]] =
                        f2h((acc[i][j][r] + bs) * mv4[j]);
                }
            }
        }
    }
}

// ---------------------------------------------------------------------------
// Attention: S-transposed fp16 MFMA flash (structure verified in R4).
// ---------------------------------------------------------------------------
__global__ __launch_bounds__(256) void attn_mfma_kernel(
    const unsigned short* __restrict__ qb,  // [32][2048][64] f16
    const unsigned short* __restrict__ kb,  // [32][2048][64] f16
    const unsigned short* __restrict__ vt,  // [32][64][2048] f16 (mask-zeroed)
    const int* __restrict__ mask,           // [2][2048]
    const unsigned short* __restrict__ mb,  // [2][2048] f16 {0,1}
    float* __restrict__ out)                // [2][2048][1024]
{
    __shared__ unsigned short Ks[2][64 * 64];
    __shared__ unsigned short Vs[2][64 * 64];
    __shared__ unsigned short Ps[4][2][16 * 64];

    const int bh   = blockIdx.y;
    const int b    = bh >> 4;
    const int h    = bh & 15;
    const int wv   = threadIdx.x >> 6;
    const int lane = threadIdx.x & 63;
    const int l15  = lane & 15;
    const int quad = lane >> 4;
    const int l7   = l15 & 7;
    const int q0w  = blockIdx.x * 128 + wv * 32;

    const unsigned short* kbh = kb + (size_t)bh * T_ * DH_;
    const unsigned short* vbh = vt + (size_t)bh * DH_ * T_;
    const unsigned short* mbb = mb + b * T_;
    const int* __restrict__ mrow = mask + b * T_;

    half8 qf[2][2];
#pragma unroll
    for (int qt = 0; qt < 2; ++qt)
#pragma unroll
        for (int c = 0; c < 2; ++c)
            qf[qt][c] = *(const half8*)(qb + ((size_t)bh * T_ + q0w + qt * 16 + l15) * DH_
                                        + c * 32 + quad * 8);

    f32x4 o[2][4];
#pragma unroll
    for (int qt = 0; qt < 2; ++qt)
#pragma unroll
        for (int n = 0; n < 4; ++n) o[qt][n] = (f32x4){0.f, 0.f, 0.f, 0.f};
    f32x4 lacc[2];
    lacc[0] = (f32x4){0.f, 0.f, 0.f, 0.f};
    lacc[1] = (f32x4){0.f, 0.f, 0.f, 0.f};

    const int lrow = lane >> 3;
    const int gch  = (lane & 7) ^ lrow;

#pragma unroll
    for (int s = 0; s < 4; ++s) {
        int j  = (wv << 2) + s;
        int rb = j & 7;
        if (j < 8) gll16(kbh + (size_t)(rb * 8 + lrow) * DH_ + gch * 8, &Ks[0][rb * 512]);
        else       gll16(vbh + (size_t)(rb * 8 + lrow) * T_  + gch * 8, &Vs[0][rb * 512]);
    }

    for (int kt = 0; kt < 32; ++kt) {
        const int cur   = kt & 1;
        const int kbase = kt * 64;
        __syncthreads();

        if (kt < 31) {
            const int nb = kbase + 64;
#pragma unroll
            for (int s = 0; s < 4; ++s) {
                int j  = (wv << 2) + s;
                int rb = j & 7;
                if (j < 8) gll16(kbh + (size_t)(nb + rb * 8 + lrow) * DH_ + gch * 8,
                                 &Ks[cur ^ 1][rb * 512]);
                else       gll16(vbh + (size_t)(rb * 8 + lrow) * T_ + nb + gch * 8,
                                 &Vs[cur ^ 1][rb * 512]);
            }
        }

        const unsigned short* Kc = &Ks[cur][0];
        const unsigned short* Vc = &Vs[cur][0];

        half8 kf[4][2];
#pragma unroll
        for (int ktile = 0; ktile < 4; ++ktile)
#pragma unroll
            for (int c = 0; c < 2; ++c)
                kf[ktile][c] = *(const half8*)(Kc + (ktile * 16 + l15) * 64
                                               + (((c * 4 + quad) ^ l7) * 8));

        half8 bmf[2];
#pragma unroll
        for (int kc = 0; kc < 2; ++kc) {
            half8 mv = *(const half8*)(mbb + kbase + kc * 32 + quad * 8);
            bmf[kc] = (l15 == 0) ? mv : (half8)0;
        }

#pragma unroll
        for (int qt = 0; qt < 2; ++qt) {
            unsigned short* Pq = &Ps[wv][qt][0];

#pragma unroll
            for (int ktile = 0; ktile < 4; ++ktile) {
                f32x4 st = (f32x4){0.f, 0.f, 0.f, 0.f};
                st = __builtin_amdgcn_mfma_f32_16x16x32_f16(kf[ktile][0], qf[qt][0], st, 0, 0, 0);
                st = __builtin_amdgcn_mfma_f32_16x16x32_f16(kf[ktile][1], qf[qt][1], st, 0, 0, 0);
                unsigned short hu[4];
#pragma unroll
                for (int r = 0; r < 4; ++r) {
                    float p = __builtin_amdgcn_exp2f(
                        fminf(st[r] * 0.18033688011112042f, 14.f));
                    hu[r] = f2h(p);
                }
                *(uint2*)(Pq + l15 * 64 + (((ktile * 2 + (quad >> 1)) ^ l7) * 8)
                          + (quad & 1) * 4) = *(const uint2*)hu;
            }

            half8 pf[2];
#pragma unroll
            for (int kc = 0; kc < 2; ++kc)
                pf[kc] = *(const half8*)(Pq + l15 * 64 + (((kc * 4 + quad) ^ l7) * 8));

            lacc[qt] = __builtin_amdgcn_mfma_f32_16x16x32_f16(pf[0], bmf[0], lacc[qt], 0, 0, 0);
            lacc[qt] = __builtin_amdgcn_mfma_f32_16x16x32_f16(pf[1], bmf[1], lacc[qt], 0, 0, 0);

#pragma unroll
            for (int n = 0; n < 4; ++n) {
#pragma unroll
                for (int kc = 0; kc < 2; ++kc) {
                    half8 vf = *(const half8*)(Vc + (n * 16 + l15) * 64
                                               + (((kc * 4 + quad) ^ l7) * 8));
                    o[qt][n] = __builtin_amdgcn_mfma_f32_16x16x32_f16(pf[kc], vf, o[qt][n], 0, 0, 0);
                }
            }
        }
    }

#pragma unroll
    for (int qt = 0; qt < 2; ++qt) {
#pragma unroll
        for (int r = 0; r < 4; ++r) {
            float lv = __shfl(lacc[qt][r], quad << 4, 64);
            int q = q0w + qt * 16 + quad * 4 + r;
            float iv = (mrow[q] != 0 && lv > 0.f) ? (1.0f / lv) : 0.f;
            float* orow = out + ((size_t)(b * T_ + q)) * C_ + h * DH_;
#pragma unroll
            for (int n = 0; n < 4; ++n)
                orow[n * 16 + l15] = o[qt][n][r] * iv;
        }
    }
}

// ---------------------------------------------------------------------------
extern "C" void kernel_launch(void* const* d_in, const int* in_sizes, int n_in,
                              void* d_out, int out_size, void* d_ws, size_t ws_size,
                              hipStream_t stream)
{
    (void)in_sizes; (void)n_in; (void)out_size; (void)ws_size;
    const float* x  = (const float*)d_in[0];
    const float* Wq = (const float*)d_in[1];
    const float* bq = (const float*)d_in[2];
    const float* Wk = (const float*)d_in[3];
    const float* bk = (const float*)d_in[4];
    const float* Wv = (const float*)d_in[5];
    const float* bv = (const float*)d_in[6];
    const int* mask = (const int*)d_in[7];
    float* out = (float*)d_out;

    const size_t NX = (size_t)B_ * T_ * C_;          // 4 Mi elements
    unsigned short* xf = (unsigned short*)d_ws;       // 8 MB fp16 x
    unsigned short* wt = xf + NX;                     // 6 MB fp16 W^T x3
    unsigned short* qb = wt + (size_t)3 * C_ * C_;    // 8 MB
    unsigned short* kb = qb + NX;                     // 8 MB
    unsigned short* vt = kb + NX;                     // 8 MB
    unsigned short* mb = vt + NX;                     // 8 KB

    prep_x_kernel<<<2048, 256, 0, stream>>>(x, xf, mask, mb);
    prep_w_kernel<<<dim3(32, 32, 3), dim3(32, 8), 0, stream>>>(Wq, Wk, Wv, wt);
    qkv_mfma_kernel<<<dim3(32, 8, 3), 256, 0, stream>>>(
        xf, wt, bq, bk, bv, mask, qb, kb, vt);
    attn_mfma_kernel<<<dim3(16, 32), 256, 0, stream>>>(qb, kb, vt, mask, mb, out);
}